// Round 12
// baseline (572.602 us; speedup 1.0000x reference)
//
#include <hip/hip_runtime.h>
#include <hip/hip_bf16.h>
#include <cstdint>

// Problem constants (fixed by the reference)
#define NN 10000      // nodes
#define NE 320000     // edges
#define NC 256        // node channels
#define OC 512        // out channels
#define K1 256        // K for edge gemm (ea) and pq gemm (x)

typedef __bf16 bf16_t;
typedef bf16_t bf16x8 __attribute__((ext_vector_type(8)));
typedef bf16_t bf16x4 __attribute__((ext_vector_type(4)));
typedef float  f32x4  __attribute__((ext_vector_type(4)));

// async global->LDS, 16B per lane; LDS dest = wave-uniform base + lane*16
__device__ __forceinline__ void gload_lds16(const void* g, void* l) {
  __builtin_amdgcn_global_load_lds(
      (const __attribute__((address_space(1))) unsigned int*)g,
      (__attribute__((address_space(3))) unsigned int*)l, 16, 0, 0);
}

// B-side column interleave: LDS tile row R holds the weight row for logical
// column (R&~63) + (R&15)*4 + ((R>>4)&3)  ->  each lane's 4 MFMA fragments
// cover 4 CONSECUTIVE output columns (vector epilogue).
__device__ __forceinline__ int permB(int R) {
  return (R & ~63) + ((R & 15) << 2) + ((R >> 4) & 3);
}

// ---------------------------------------------------------------------------
// Prep: zero agg/deg/cursor/sums, xb=bf16(x), build transposed bf16 weights.
// ---------------------------------------------------------------------------
__global__ void k_prep(const float* __restrict__ x,
                       const float* __restrict__ W1,
                       const float* __restrict__ W2,
                       bf16_t* __restrict__ xb,
                       bf16_t* __restrict__ w1abt,
                       bf16_t* __restrict__ w1ct,
                       bf16_t* __restrict__ w2t,
                       float* __restrict__ agg,
                       int* __restrict__ deg,
                       int* __restrict__ cursor,
                       float* __restrict__ sums) {
  const int stride = gridDim.x * blockDim.x;
  for (int i = blockIdx.x * blockDim.x + threadIdx.x; i < NN * OC; i += stride) {
    agg[i] = 0.0f;
    if (i < NN * NC) xb[i] = (bf16_t)x[i];
    if (i < 1024 * K1) {
      const int n = i >> 8, k = i & 255;
      float w;
      if (n < OC) w = W1[(size_t)k * OC + n] - W1[(size_t)(k + NC) * OC + n];
      else        w = W1[(size_t)(k + NC) * OC + (n - OC)];
      w1abt[i] = (bf16_t)w;
    }
    if (i < OC * K1) {
      const int n = i >> 8, k = i & 255;
      w1ct[i] = (bf16_t)W1[(size_t)(512 + k) * OC + n];
    }
    if (i < OC * OC) {
      const int n = i >> 9, k = i & 511;
      w2t[i] = (bf16_t)W2[(size_t)k * OC + n];
    }
    if (i < NN) { deg[i] = 0; cursor[i] = 0; }
    if (i < 1024) sums[i] = 0.0f;
  }
}

__global__ void k_deg(const int* __restrict__ dstIdx, int* __restrict__ deg) {
  const int i = blockIdx.x * blockDim.x + threadIdx.x;
  if (i < NE) atomicAdd(&deg[dstIdx[i]], 1);
}

// Single-block exclusive prefix sum over NN bins.
__global__ void k_scan(const int* __restrict__ deg, int* __restrict__ offs) {
  __shared__ int carry;
  __shared__ int wsum[4];
  if (threadIdx.x == 0) carry = 0;
  __syncthreads();
  const int lane = threadIdx.x & 63, w = threadIdx.x >> 6;
  for (int base = 0; base < NN; base += 256) {
    const int i = base + threadIdx.x;
    const int v = (i < NN) ? deg[i] : 0;
    int s = v;
#pragma unroll
    for (int d = 1; d < 64; d <<= 1) { int t = __shfl_up(s, d); if (lane >= d) s += t; }
    if (lane == 63) wsum[w] = s;
    __syncthreads();
    int woff = 0;
    for (int j = 0; j < w; j++) woff += wsum[j];
    const int incl = s + woff + carry;
    if (i < NN) offs[i] = incl - v;  // exclusive
    __syncthreads();
    if (threadIdx.x == 255) carry = incl;
    __syncthreads();
  }
}

// Counting-sort scatter: edges grouped by dst.
__global__ void k_scatter(const int* __restrict__ srcIdx, const int* __restrict__ dstIdx,
                          const int* __restrict__ offs, int* __restrict__ cursor,
                          int* __restrict__ eperm, int* __restrict__ sdst,
                          int* __restrict__ ssrc) {
  const int e = blockIdx.x * blockDim.x + threadIdx.x;
  if (e < NE) {
    const int d = dstIdx[e];
    const int pos = offs[d] + atomicAdd(&cursor[d], 1);
    eperm[pos] = e;
    sdst[pos] = d;
    ssrc[pos] = srcIdx[e];
  }
}

// ---------------------------------------------------------------------------
// Node-level PQ GEMM: [P | Q] = xb @ w1abt^T.  M=10000, K=256, N=1024.
// ---------------------------------------------------------------------------
__global__ __launch_bounds__(256) void k_pq(
    const bf16_t* __restrict__ xb,     // [NN][256]
    const bf16_t* __restrict__ w1abt,  // [1024][256]
    const float*  __restrict__ b1,
    float*        __restrict__ P,      // [NN][512] fp32 (= x@W1a' + b1)
    bf16_t*       __restrict__ Qb) {   // [NN][512] bf16 (= x@W1b)
  __shared__ bf16_t sA[128 * 64];
  __shared__ bf16_t sB[128 * 64];

  const int tid = threadIdx.x;
  const int cb = blockIdx.x & 7, rblk = blockIdx.x >> 3;
  const int r0 = rblk * 128, n0 = cb * 128;
  const int lane = tid & 63, wid = tid >> 6;
  const int mbase = (wid >> 1) * 64, nbase = (wid & 1) * 64;
  const int lr = lane >> 3, ls = lane & 7, slog = ls ^ lr;
  const int g = lane >> 4;

  f32x4 acc[4][4];
#pragma unroll
  for (int mi = 0; mi < 4; mi++)
#pragma unroll
    for (int ni = 0; ni < 4; ni++) acc[mi][ni] = (f32x4){0.f, 0.f, 0.f, 0.f};

  for (int kb = 0; kb < K1; kb += 64) {
#pragma unroll
    for (int i = 0; i < 4; i++) {
      const int row = wid * 32 + i * 8;          // wave-uniform
      int grow = r0 + row + lr;                  // per-lane source row
      if (grow > NN - 1) grow = NN - 1;          // clamp (guarded on write)
      gload_lds16(xb + (size_t)grow * NC + kb + slog * 8, &sA[row * 64]);
      gload_lds16(w1abt + (size_t)(n0 + permB(row + lr)) * K1 + kb + slog * 8,
                  &sB[row * 64]);
    }
    __syncthreads();
#pragma unroll
    for (int kk = 0; kk < 2; kk++) {
      const int sl = kk * 4 + g;
      bf16x8 av[4], bv[4];
#pragma unroll
      for (int mi = 0; mi < 4; mi++) {
        const int rA = mbase + mi * 16 + (lane & 15);
        av[mi] = *(const bf16x8*)&sA[rA * 64 + ((sl ^ (rA & 7)) * 8)];
      }
#pragma unroll
      for (int ni = 0; ni < 4; ni++) {
        const int rB = nbase + ni * 16 + (lane & 15);
        bv[ni] = *(const bf16x8*)&sB[rB * 64 + ((sl ^ (rB & 7)) * 8)];
      }
#pragma unroll
      for (int mi = 0; mi < 4; mi++)
#pragma unroll
        for (int ni = 0; ni < 4; ni++)
          acc[mi][ni] = __builtin_amdgcn_mfma_f32_16x16x32_bf16(av[mi], bv[ni], acc[mi][ni], 0, 0, 0);
    }
    __syncthreads();
  }

  const int col0 = n0 + nbase + (lane & 15) * 4;
  f32x4 b1v = {0.f, 0.f, 0.f, 0.f};
  if (col0 < OC) b1v = *(const f32x4*)&b1[col0];
#pragma unroll
  for (int mi = 0; mi < 4; mi++) {
#pragma unroll
    for (int q = 0; q < 4; q++) {
      const int grow = r0 + mbase + mi * 16 + g * 4 + q;
      if (grow < NN) {
        if (col0 < OC) {
          f32x4 v;
#pragma unroll
          for (int j = 0; j < 4; j++) v[j] = acc[mi][j][q] + b1v[j];
          *(f32x4*)&P[(size_t)grow * OC + col0] = v;
        } else {
          bf16x4 v;
#pragma unroll
          for (int j = 0; j < 4; j++) v[j] = (bf16_t)acc[mi][j][q];
          *(bf16x4*)&Qb[(size_t)grow * OC + (col0 - OC)] = v;
        }
      }
    }
  }
}

// ===========================================================================
// SPLIT PATH (a): k_edge_h — R7's pipelined GEMM, epilogue = streaming H
// store.  H[e][col] = relu(R + P[dst] + Q[src]) in bf16; no atomics.
// ===========================================================================
__global__ __launch_bounds__(256, 2) void k_edge_h(
    const float*  __restrict__ ea,     // [NE][256] f32
    const bf16_t* __restrict__ w1ct,   // [512][256] bf16
    const float*  __restrict__ P,      // [NN][512] f32 (b1 folded)
    const bf16_t* __restrict__ Qb,     // [NN][512] bf16
    const int*    __restrict__ eperm,
    const int*    __restrict__ sdst,
    const int*    __restrict__ ssrc,
    bf16_t*       __restrict__ H) {    // [NE][512] bf16 (sorted edge order)
  __shared__ bf16_t sM[2][128 * 64];   // ea tile, double-buffered (32 KB)
  __shared__ bf16_t sW[2][128 * 64];   // W1c tile, double-buffered (32 KB)
  __shared__ int sDst[128];
  __shared__ int sSrc[128];
  __shared__ int sE[128];

  const int bid = (blockIdx.x & 7) * 1250 + (blockIdx.x >> 3);  // XCD swizzle
  const int cb = bid & 3, eblk = bid >> 2;
  const int e0 = eblk * 128, n0 = cb * 128;

  const int tid = threadIdx.x;
  if (tid < 128) {
    sDst[tid] = sdst[e0 + tid];
    sSrc[tid] = ssrc[e0 + tid];
    sE[tid]   = eperm[e0 + tid];
  }
  __syncthreads();

  const int lane = tid & 63, wid = tid >> 6;
  const int mbase = (wid >> 1) * 64, nbase = (wid & 1) * 64;
  const int g = lane >> 4, r = lane & 15;
  const int lr = lane >> 3, ls = lane & 7, slogW = ls ^ lr;
  const int mrow = tid >> 1, qd = tid & 1;
  const int msw = mrow & 7;
  const float* eaRow = ea + (size_t)sE[mrow] * NC;

#define STAGE_W(kt, b)                                                        \
  _Pragma("unroll") for (int i = 0; i < 4; i++) {                             \
    const int rowb = wid * 32 + i * 8;                                        \
    gload_lds16(w1ct + (size_t)(n0 + permB(rowb + lr)) * K1 + (kt)*64 + slogW * 8, \
                &sW[b][rowb * 64]);                                           \
  }
#define LOAD_A(kt)                                                            \
  _Pragma("unroll") for (int j = 0; j < 8; j++)                               \
      a[j] = *(const f32x4*)(eaRow + (kt)*64 + qd * 32 + j * 4);
#define WRITE_M(b)                                                            \
  _Pragma("unroll") for (int tt = 0; tt < 4; tt++) {                          \
    const int slot = qd * 4 + tt;                                             \
    bf16x8 v;                                                                 \
    _Pragma("unroll") for (int jj = 0; jj < 4; jj++) {                        \
      v[jj] = (bf16_t)a[tt * 2][jj];                                          \
      v[4 + jj] = (bf16_t)a[tt * 2 + 1][jj];                                  \
    }                                                                         \
    *(bf16x8*)&sM[b][mrow * 64 + ((slot ^ msw) * 8)] = v;                     \
  }

  f32x4 a[8];

  // prologue: stage K-step 0; prefetch P/Q gathers
  STAGE_W(0, 0);
  LOAD_A(0);

  const int col0 = n0 + nbase + r * 4;
  f32x4  Pp[4][4];
  bf16x4 Qp[4][4];
#pragma unroll
  for (int mi = 0; mi < 4; mi++) {
    const int rbase = mbase + mi * 16 + g * 4;
#pragma unroll
    for (int q = 0; q < 4; q++) {
      Pp[mi][q] = *(const f32x4*)&P[(size_t)sDst[rbase + q] * OC + col0];
      Qp[mi][q] = *(const bf16x4*)&Qb[(size_t)sSrc[rbase + q] * OC + col0];
    }
  }

  WRITE_M(0);

  f32x4 acc[4][4];
#pragma unroll
  for (int mi = 0; mi < 4; mi++)
#pragma unroll
    for (int ni = 0; ni < 4; ni++) acc[mi][ni] = (f32x4){0.f, 0.f, 0.f, 0.f};

#pragma unroll
  for (int t = 0; t < 4; t++) {
    const int b = t & 1;
    __syncthreads();
    if (t < 3) { STAGE_W(t + 1, b ^ 1); LOAD_A(t + 1); }
#pragma unroll
    for (int kk = 0; kk < 2; kk++) {
      const int sl = kk * 4 + g;
      bf16x8 av[4], bv[4];
#pragma unroll
      for (int mi = 0; mi < 4; mi++) {
        const int rA = mbase + mi * 16 + r;
        av[mi] = *(const bf16x8*)&sM[b][rA * 64 + ((sl ^ (rA & 7)) * 8)];
      }
#pragma unroll
      for (int ni = 0; ni < 4; ni++) {
        const int rB = nbase + ni * 16 + r;
        bv[ni] = *(const bf16x8*)&sW[b][rB * 64 + ((sl ^ (rB & 7)) * 8)];
      }
#pragma unroll
      for (int mi = 0; mi < 4; mi++)
#pragma unroll
        for (int ni = 0; ni < 4; ni++)
          acc[mi][ni] = __builtin_amdgcn_mfma_f32_16x16x32_bf16(av[mi], bv[ni], acc[mi][ni], 0, 0, 0);
    }
    if (t < 3) { WRITE_M(b ^ 1); }
  }
#undef STAGE_W
#undef LOAD_A
#undef WRITE_M

  // epilogue: relu(acc + P + Q) -> bf16 streaming store (no atomics)
#pragma unroll
  for (int mi = 0; mi < 4; mi++) {
#pragma unroll
    for (int q = 0; q < 4; q++) {
      const int row = e0 + mbase + mi * 16 + g * 4 + q;
      bf16x4 hv;
#pragma unroll
      for (int j = 0; j < 4; j++)
        hv[j] = (bf16_t)fmaxf(acc[mi][j][q] + Pp[mi][q][j] + (float)Qp[mi][q][j], 0.f);
      *(bf16x4*)&H[(size_t)row * OC + col0] = hv;
    }
  }
}

// ===========================================================================
// SPLIT PATH (b): k_seg — per-node segment sum of contiguous H rows.
// One wave per node; lane covers 8 consecutive cols; pure streaming.
// ===========================================================================
__global__ __launch_bounds__(256) void k_seg(
    const bf16_t* __restrict__ H,
    const int*    __restrict__ offs,
    const int*    __restrict__ deg,
    float*        __restrict__ agg) {
  const int lane = threadIdx.x & 63, wid = threadIdx.x >> 6;
  const int n = blockIdx.x * 4 + wid;          // 2500 blocks x 4 waves = NN
  if (n >= NN) return;
  const int s = offs[n], d = deg[n];
  float acc[8] = {0.f, 0.f, 0.f, 0.f, 0.f, 0.f, 0.f, 0.f};
  const bf16_t* p = H + (size_t)s * OC + lane * 8;
  for (int i = 0; i < d; i++) {
    const bf16x8 v = *(const bf16x8*)p;
    p += OC;
#pragma unroll
    for (int j = 0; j < 8; j++) acc[j] += (float)v[j];
  }
  float* o = agg + (size_t)n * OC + lane * 8;
  f32x4 a0, a1;
#pragma unroll
  for (int j = 0; j < 4; j++) { a0[j] = acc[j]; a1[j] = acc[4 + j]; }
  *(f32x4*)o = a0;
  *(f32x4*)(o + 4) = a1;
}

// ===========================================================================
// FUSED FALLBACK: R7's k_edge_gemm verbatim (373 µs champion) — used when
// ws_size can't fit H.
// ===========================================================================
__global__ __launch_bounds__(256, 2) void k_edge_gemm_fused(
    const float*  __restrict__ ea,
    const bf16_t* __restrict__ w1ct,
    const float*  __restrict__ P,
    const bf16_t* __restrict__ Qb,
    const int*    __restrict__ eperm,
    const int*    __restrict__ sdst,
    const int*    __restrict__ ssrc,
    float*        __restrict__ agg) {
  __shared__ bf16_t sM[2][128 * 64];
  __shared__ bf16_t sW[2][128 * 64];
  __shared__ int sDst[128];
  __shared__ int sSrc[128];
  __shared__ int sE[128];

  const int bid = (blockIdx.x & 7) * 1250 + (blockIdx.x >> 3);
  const int cb = bid & 3, eblk = bid >> 2;
  const int e0 = eblk * 128, n0 = cb * 128;

  const int tid = threadIdx.x;
  if (tid < 128) {
    sDst[tid] = sdst[e0 + tid];
    sSrc[tid] = ssrc[e0 + tid];
    sE[tid]   = eperm[e0 + tid];
  }
  __syncthreads();

  const int lane = tid & 63, wid = tid >> 6;
  const int mbase = (wid >> 1) * 64, nbase = (wid & 1) * 64;
  const int g = lane >> 4, r = lane & 15;
  const int lr = lane >> 3, ls = lane & 7, slogW = ls ^ lr;
  const int mrow = tid >> 1, qd = tid & 1;
  const int msw = mrow & 7;
  const float* eaRow = ea + (size_t)sE[mrow] * NC;

#define STAGE_W(kt, b)                                                        \
  _Pragma("unroll") for (int i = 0; i < 4; i++) {                             \
    const int rowb = wid * 32 + i * 8;                                        \
    gload_lds16(w1ct + (size_t)(n0 + permB(rowb + lr)) * K1 + (kt)*64 + slogW * 8, \
                &sW[b][rowb * 64]);                                           \
  }
#define LOAD_A(kt)                                                            \
  _Pragma("unroll") for (int j = 0; j < 8; j++)                               \
      a[j] = *(const f32x4*)(eaRow + (kt)*64 + qd * 32 + j * 4);
#define WRITE_M(b)                                                            \
  _Pragma("unroll") for (int tt = 0; tt < 4; tt++) {                          \
    const int slot = qd * 4 + tt;                                             \
    bf16x8 v;                                                                 \
    _Pragma("unroll") for (int jj = 0; jj < 4; jj++) {                        \
      v[jj] = (bf16_t)a[tt * 2][jj];                                          \
      v[4 + jj] = (bf16_t)a[tt * 2 + 1][jj];                                  \
    }                                                                         \
    *(bf16x8*)&sM[b][mrow * 64 + ((slot ^ msw) * 8)] = v;                     \
  }

  f32x4 a[8];
  STAGE_W(0, 0);
  LOAD_A(0);

  const int col0 = n0 + nbase + r * 4;
  f32x4  Pp[4][4];
  bf16x4 Qp[4][4];
#pragma unroll
  for (int mi = 0; mi < 4; mi++) {
    const int rbase = mbase + mi * 16 + g * 4;
#pragma unroll
    for (int q = 0; q < 4; q++) {
      Pp[mi][q] = *(const f32x4*)&P[(size_t)sDst[rbase + q] * OC + col0];
      Qp[mi][q] = *(const bf16x4*)&Qb[(size_t)sSrc[rbase + q] * OC + col0];
    }
  }

  WRITE_M(0);

  f32x4 acc[4][4];
#pragma unroll
  for (int mi = 0; mi < 4; mi++)
#pragma unroll
    for (int ni = 0; ni < 4; ni++) acc[mi][ni] = (f32x4){0.f, 0.f, 0.f, 0.f};

#pragma unroll
  for (int t = 0; t < 4; t++) {
    const int b = t & 1;
    __syncthreads();
    if (t < 3) { STAGE_W(t + 1, b ^ 1); LOAD_A(t + 1); }
#pragma unroll
    for (int kk = 0; kk < 2; kk++) {
      const int sl = kk * 4 + g;
      bf16x8 av[4], bv[4];
#pragma unroll
      for (int mi = 0; mi < 4; mi++) {
        const int rA = mbase + mi * 16 + r;
        av[mi] = *(const bf16x8*)&sM[b][rA * 64 + ((sl ^ (rA & 7)) * 8)];
      }
#pragma unroll
      for (int ni = 0; ni < 4; ni++) {
        const int rB = nbase + ni * 16 + r;
        bv[ni] = *(const bf16x8*)&sW[b][rB * 64 + ((sl ^ (rB & 7)) * 8)];
      }
#pragma unroll
      for (int mi = 0; mi < 4; mi++)
#pragma unroll
        for (int ni = 0; ni < 4; ni++)
          acc[mi][ni] = __builtin_amdgcn_mfma_f32_16x16x32_bf16(av[mi], bv[ni], acc[mi][ni], 0, 0, 0);
    }
    if (t < 3) { WRITE_M(b ^ 1); }
  }
#undef STAGE_W
#undef LOAD_A
#undef WRITE_M

#pragma unroll
  for (int mi = 0; mi < 4; mi++) {
    const int rbase = mbase + mi * 16 + g * 4;
    const int d0 = sDst[rbase],     d1 = sDst[rbase + 1];
    const int d2 = sDst[rbase + 2], d3 = sDst[rbase + 3];
    const int headId = d0, tailId = d3;
    const bool b1q = (d1 != d0), b2q = (d2 != d1), b3q = (d3 != d2);
    const bool seen = b1q | b2q | b3q;
    bool match[3];
#pragma unroll
    for (int j = 0; j < 3; j++) {
      const int tIdj = __shfl(tailId, (lane & 15) | (j << 4));
      match[j] = (j < g) && (tIdj == headId);
    }
    const int nextHead = __shfl(headId, (lane + 16) & 63);
    const bool endsHere = (g == 3) || (nextHead != tailId);

    f32x4 v0, v1, v2, v3;
#pragma unroll
    for (int j = 0; j < 4; j++) {
      v0[j] = fmaxf(acc[mi][j][0] + Pp[mi][0][j] + (float)Qp[mi][0][j], 0.f);
      v1[j] = fmaxf(acc[mi][j][1] + Pp[mi][1][j] + (float)Qp[mi][1][j], 0.f);
      v2[j] = fmaxf(acc[mi][j][2] + Pp[mi][2][j] + (float)Qp[mi][2][j], 0.f);
      v3[j] = fmaxf(acc[mi][j][3] + Pp[mi][3][j] + (float)Qp[mi][3][j], 0.f);
    }

    f32x4 head = {0.f, 0.f, 0.f, 0.f}, run = v0;
    bool first = true;
    if (b1q) { head = run; first = false; run = v1; } else run += v1;
    if (b2q) {
      if (first) { head = run; first = false; }
      else {
        float* base = agg + (size_t)d1 * OC + col0;
#pragma unroll
        for (int j = 0; j < 4; j++) if (run[j] != 0.f) atomicAdd(base + j, run[j]);
      }
      run = v2;
    } else run += v2;
    if (b3q) {
      if (first) { head = run; first = false; }
      else {
        float* base = agg + (size_t)d2 * OC + col0;
#pragma unroll
        for (int j = 0; j < 4; j++) if (run[j] != 0.f) atomicAdd(base + j, run[j]);
      }
      run = v3;
    } else run += v3;
    const f32x4 tailSum = run;

    f32x4 inc = {0.f, 0.f, 0.f, 0.f};
#pragma unroll
    for (int jg = 0; jg < 3; jg++) {
      f32x4 ts;
#pragma unroll
      for (int c = 0; c < 4; c++) ts[c] = __shfl(tailSum[c], (lane & 15) | (jg << 4));
      if (match[jg]) inc += ts;
    }
    if (seen) {
      float* base = agg + (size_t)headId * OC + col0;
#pragma unroll
      for (int j = 0; j < 4; j++) {
        const float h = head[j] + inc[j];
        if (h != 0.f) atomicAdd(base + j, h);
      }
    }
    if (endsHere) {
      float* base = agg + (size_t)tailId * OC + col0;
#pragma unroll
      for (int j = 0; j < 4; j++) {
        const float t2 = tailSum[j] + (seen ? 0.f : inc[j]);
        if (t2 != 0.f) atomicAdd(base + j, t2);
      }
    }
  }
}

// ---------------------------------------------------------------------------
// Node GEMM: out = agg @ W2 + deg * b2   (10000x512 @ 512x512)
// ---------------------------------------------------------------------------
__global__ __launch_bounds__(256) void k_node_gemm(
    const float*  __restrict__ agg,
    const bf16_t* __restrict__ w2t,
    const float*  __restrict__ b2,
    const int*    __restrict__ deg,
    float*        __restrict__ out) {
  __shared__ bf16_t sM[128 * 72];
  __shared__ bf16_t sW[128 * 72];

  const int tid  = threadIdx.x;
  const int bid  = blockIdx.x;
  const int cb   = bid & 3;
  const int rblk = bid >> 2;
  const int r0   = rblk * 128;
  const int n0   = cb * 128;

  const int lane  = tid & 63, wid = tid >> 6;
  const int mbase = (wid >> 1) * 64, nbase = (wid & 1) * 64;
  const int se = tid >> 1;
  const int sk = (tid & 1) * 32;
  const int arow  = r0 + se;
  const bool rowok = arow < NN;

  f32x4 acc[4][4];
#pragma unroll
  for (int mi = 0; mi < 4; mi++)
#pragma unroll
    for (int ni = 0; ni < 4; ni++) acc[mi][ni] = (f32x4){0.f, 0.f, 0.f, 0.f};

  for (int kb = 0; kb < OC; kb += 64) {
    {
      bf16x8* dst = (bf16x8*)&sM[se * 72 + sk];
      if (rowok) {
        const float* pf = agg + (size_t)arow * OC + kb + sk;
        f32x4 f[8];
#pragma unroll
        for (int i = 0; i < 8; i++) f[i] = *(const f32x4*)(pf + i * 4);
#pragma unroll
        for (int i = 0; i < 4; i++) {
          bf16x8 v;
#pragma unroll
          for (int j = 0; j < 4; j++) {
            v[j]     = (bf16_t)f[2 * i][j];
            v[4 + j] = (bf16_t)f[2 * i + 1][j];
          }
          dst[i] = v;
        }
      } else {
        bf16x8 z = {};
        dst[0] = z; dst[1] = z; dst[2] = z; dst[3] = z;
      }
    }
    {
      const bf16_t* pw = w2t + (size_t)(n0 + permB(se)) * OC + kb + sk;
      bf16x8* dst = (bf16x8*)&sW[se * 72 + sk];
      dst[0] = *(const bf16x8*)(pw);
      dst[1] = *(const bf16x8*)(pw + 8);
      dst[2] = *(const bf16x8*)(pw + 16);
      dst[3] = *(const bf16x8*)(pw + 24);
    }
    __syncthreads();
#pragma unroll
    for (int kk = 0; kk < 2; kk++) {
      const int krd = kk * 32 + (lane >> 4) * 8;
      bf16x8 av[4], bv[4];
#pragma unroll
      for (int mi = 0; mi < 4; mi++)
        av[mi] = *(const bf16x8*)&sM[(mbase + mi * 16 + (lane & 15)) * 72 + krd];
#pragma unroll
      for (int ni = 0; ni < 4; ni++)
        bv[ni] = *(const bf16x8*)&sW[(nbase + ni * 16 + (lane & 15)) * 72 + krd];
#pragma unroll
      for (int mi = 0; mi < 4; mi++)
#pragma unroll
        for (int ni = 0; ni < 4; ni++)
          acc[mi][ni] = __builtin_amdgcn_mfma_f32_16x16x32_bf16(av[mi], bv[ni], acc[mi][ni], 0, 0, 0);
    }
    __syncthreads();
  }

  const int col0 = n0 + nbase + (lane & 15) * 4;
  const f32x4 b2v = *(const f32x4*)&b2[col0];
  const int g = lane >> 4;
#pragma unroll
  for (int mi = 0; mi < 4; mi++) {
#pragma unroll
    for (int q = 0; q < 4; q++) {
      const int row = r0 + mbase + mi * 16 + g * 4 + q;
      if (row < NN) {
        const float dg = (float)deg[row];
        f32x4 v;
#pragma unroll
        for (int j = 0; j < 4; j++) v[j] = acc[mi][j][q] + b2v[j] * dg;
        *(f32x4*)&out[(size_t)row * OC + col0] = v;
      }
    }
  }
}

// ---------------------------------------------------------------------------
// BatchNorm: stats, finalize, apply(+relu).
// ---------------------------------------------------------------------------
__global__ void k_bn_stats(const float* __restrict__ out, float* __restrict__ sums) {
  const int c = threadIdx.x;
  float s1 = 0.f, q1 = 0.f, s2 = 0.f, q2 = 0.f;
  for (int n = blockIdx.x; n < NN; n += gridDim.x) {
    const float* row = out + (size_t)n * OC;
    const float v1 = row[c], v2 = row[c + 256];
    s1 += v1; q1 += v1 * v1;
    s2 += v2; q2 += v2 * v2;
  }
  atomicAdd(&sums[c], s1);        atomicAdd(&sums[OC + c], q1);
  atomicAdd(&sums[c + 256], s2);  atomicAdd(&sums[OC + c + 256], q2);
}

__global__ void k_bn_finalize(const float* __restrict__ sums,
                              const float* __restrict__ gamma,
                              const float* __restrict__ beta,
                              float* __restrict__ scale,
                              float* __restrict__ shift) {
  const int c = threadIdx.x;
  const float mean = sums[c] * (1.0f / NN);
  const float var  = sums[OC + c] * (1.0f / NN) - mean * mean;
  const float r    = rsqrtf(var + 1e-5f);
  const float sc   = r * gamma[c];
  scale[c] = sc;
  shift[c] = beta[c] - mean * sc;
}

__global__ void k_bn_apply(float* __restrict__ out,
                           const float* __restrict__ scale,
                           const float* __restrict__ shift) {
  const int i = blockIdx.x * blockDim.x + threadIdx.x;
  f32x4 v = *((const f32x4*)out + i);
  const int c = (i & 127) << 2;
  f32x4 r;
#pragma unroll
  for (int j = 0; j < 4; j++) r[j] = fmaxf(v[j] * scale[c + j] + shift[c + j], 0.0f);
  *((f32x4*)out + i) = r;
}

// ---------------------------------------------------------------------------
extern "C" void kernel_launch(void* const* d_in, const int* in_sizes, int n_in,
                              void* d_out, int out_size, void* d_ws, size_t ws_size,
                              hipStream_t stream) {
  const float* x     = (const float*)d_in[0];
  const int*   ei    = (const int*)d_in[1];
  const float* ea    = (const float*)d_in[2];
  const float* W1    = (const float*)d_in[3];
  const float* b1    = (const float*)d_in[4];
  const float* W2    = (const float*)d_in[5];
  const float* b2    = (const float*)d_in[6];
  const float* gamma = (const float*)d_in[7];
  const float* beta  = (const float*)d_in[8];
  float* out = (float*)d_out;

  char* ws = (char*)d_ws;
  float*  agg    = (float*)(ws);                    // 20,480,000 B
  float*  P      = (float*)(ws + 20480000);         // 20,480,000 B
  bf16_t* Qb     = (bf16_t*)(ws + 40960000);        // 10,240,000 B
  bf16_t* xb     = (bf16_t*)(ws + 51200000);        //  5,120,000 B
  bf16_t* w1abt  = (bf16_t*)(ws + 56320000);        //    524,288 B
  bf16_t* w1ct   = (bf16_t*)(ws + 56844288);        //    262,144 B
  bf16_t* w2t    = (bf16_t*)(ws + 57106432);        //    524,288 B
  int*    deg    = (int*)(ws + 57630720);           //     40,000 B
  int*    offs   = (int*)(ws + 57670720);           //     40,000 B
  int*    cursor = (int*)(ws + 57710720);           //     40,000 B
  float*  sums   = (float*)(ws + 57750720);         //      4,096 B
  float*  scale  = (float*)(ws + 57754816);         //      2,048 B
  float*  shift  = (float*)(ws + 57756864);         //      2,048 B
  int*    eperm  = (int*)(ws + 57758912);           //  1,280,000 B
  int*    sdst   = (int*)(ws + 59038912);           //  1,280,000 B
  int*    ssrc   = (int*)(ws + 60318912);           //  1,280,000 B
  const size_t H_OFF = 61598912;                    // 16B-aligned
  const size_t WS_NEEDED = H_OFF + (size_t)NE * OC * sizeof(bf16_t);  // 389,278,912

  const int* srcIdx = ei;
  const int* dstIdx = ei + NE;

  k_prep<<<4096, 256, 0, stream>>>(x, W1, W2, xb, w1abt, w1ct, w2t, agg, deg, cursor, sums);
  k_deg<<<(NE + 255) / 256, 256, 0, stream>>>(dstIdx, deg);
  k_scan<<<1, 256, 0, stream>>>(deg, offs);
  k_scatter<<<(NE + 255) / 256, 256, 0, stream>>>(srcIdx, dstIdx, offs, cursor,
                                                  eperm, sdst, ssrc);
  k_pq<<<((NN + 127) / 128) * 8, 256, 0, stream>>>(xb, w1abt, b1, P, Qb);

  if (ws_size >= WS_NEEDED) {
    // split path: dense H store (no atomics) + per-node segment sum
    bf16_t* H = (bf16_t*)(ws + H_OFF);
    k_edge_h<<<(NE / 128) * 4, 256, 0, stream>>>(ea, w1ct, P, Qb, eperm, sdst, ssrc, H);
    k_seg<<<(NN + 3) / 4, 256, 0, stream>>>(H, offs, deg, agg);
  } else {
    // fused fallback (R7 champion)
    k_edge_gemm_fused<<<(NE / 128) * 4, 256, 0, stream>>>(ea, w1ct, P, Qb, eperm,
                                                          sdst, ssrc, agg);
  }

  k_node_gemm<<<((NN + 127) / 128) * 4, 256, 0, stream>>>(agg, w2t, b2, deg, out);
  k_bn_stats<<<256, 256, 0, stream>>>(out, sums);
  k_bn_finalize<<<1, 512, 0, stream>>>(sums, gamma, beta, scale, shift);
  k_bn_apply<<<(NN * OC / 4 + 255) / 256, 256, 0, stream>>>(out, scale, shift);
}

// Round 13
// 571.452 us; speedup vs baseline: 1.0020x; 1.0020x over previous
//
#include <hip/hip_runtime.h>
#include <hip/hip_bf16.h>
#include <cstdint>

// Problem constants (fixed by the reference)
#define NN 10000      // nodes
#define NE 320000     // edges
#define NC 256        // node channels
#define OC 512        // out channels
#define K1 256        // K for edge gemm (ea) and pq gemm (x)

typedef __bf16 bf16_t;
typedef bf16_t bf16x8 __attribute__((ext_vector_type(8)));
typedef bf16_t bf16x4 __attribute__((ext_vector_type(4)));
typedef float  f32x4  __attribute__((ext_vector_type(4)));

// async global->LDS, 16B per lane; LDS dest = wave-uniform base + lane*16;
// global source address is PER-LANE (swizzled layouts via source pre-swizzle).
__device__ __forceinline__ void gload_lds16(const void* g, void* l) {
  __builtin_amdgcn_global_load_lds(
      (const __attribute__((address_space(1))) unsigned int*)g,
      (__attribute__((address_space(3))) unsigned int*)l, 16, 0, 0);
}

// B-side column interleave: LDS tile row R holds the weight row for logical
// column (R&~63) + (R&15)*4 + ((R>>4)&3)  ->  each lane's 4 MFMA fragments
// cover 4 CONSECUTIVE output columns (vector epilogue).
__device__ __forceinline__ int permB(int R) {
  return (R & ~63) + ((R & 15) << 2) + ((R >> 4) & 3);
}

// ---------------------------------------------------------------------------
// Prep: zero agg/deg/cursor/sums, xb=bf16(x), build transposed bf16 weights.
// ---------------------------------------------------------------------------
__global__ void k_prep(const float* __restrict__ x,
                       const float* __restrict__ W1,
                       const float* __restrict__ W2,
                       bf16_t* __restrict__ xb,
                       bf16_t* __restrict__ w1abt,
                       bf16_t* __restrict__ w1ct,
                       bf16_t* __restrict__ w2t,
                       float* __restrict__ agg,
                       int* __restrict__ deg,
                       int* __restrict__ cursor,
                       float* __restrict__ sums) {
  const int stride = gridDim.x * blockDim.x;
  for (int i = blockIdx.x * blockDim.x + threadIdx.x; i < NN * OC; i += stride) {
    agg[i] = 0.0f;
    if (i < NN * NC) xb[i] = (bf16_t)x[i];
    if (i < 1024 * K1) {
      const int n = i >> 8, k = i & 255;
      float w;
      if (n < OC) w = W1[(size_t)k * OC + n] - W1[(size_t)(k + NC) * OC + n];
      else        w = W1[(size_t)(k + NC) * OC + (n - OC)];
      w1abt[i] = (bf16_t)w;
    }
    if (i < OC * K1) {
      const int n = i >> 8, k = i & 255;
      w1ct[i] = (bf16_t)W1[(size_t)(512 + k) * OC + n];
    }
    if (i < OC * OC) {
      const int n = i >> 9, k = i & 511;
      w2t[i] = (bf16_t)W2[(size_t)k * OC + n];
    }
    if (i < NN) { deg[i] = 0; cursor[i] = 0; }
    if (i < 1024) sums[i] = 0.0f;
  }
}

__global__ void k_deg(const int* __restrict__ dstIdx, int* __restrict__ deg) {
  const int i = blockIdx.x * blockDim.x + threadIdx.x;
  if (i < NE) atomicAdd(&deg[dstIdx[i]], 1);
}

// Single-block exclusive prefix sum over NN bins.
__global__ void k_scan(const int* __restrict__ deg, int* __restrict__ offs) {
  __shared__ int carry;
  __shared__ int wsum[4];
  if (threadIdx.x == 0) carry = 0;
  __syncthreads();
  const int lane = threadIdx.x & 63, w = threadIdx.x >> 6;
  for (int base = 0; base < NN; base += 256) {
    const int i = base + threadIdx.x;
    const int v = (i < NN) ? deg[i] : 0;
    int s = v;
#pragma unroll
    for (int d = 1; d < 64; d <<= 1) { int t = __shfl_up(s, d); if (lane >= d) s += t; }
    if (lane == 63) wsum[w] = s;
    __syncthreads();
    int woff = 0;
    for (int j = 0; j < w; j++) woff += wsum[j];
    const int incl = s + woff + carry;
    if (i < NN) offs[i] = incl - v;  // exclusive
    __syncthreads();
    if (threadIdx.x == 255) carry = incl;
    __syncthreads();
  }
}

// Counting-sort scatter: edges grouped by dst.
__global__ void k_scatter(const int* __restrict__ srcIdx, const int* __restrict__ dstIdx,
                          const int* __restrict__ offs, int* __restrict__ cursor,
                          int* __restrict__ eperm, int* __restrict__ sdst,
                          int* __restrict__ ssrc) {
  const int e = blockIdx.x * blockDim.x + threadIdx.x;
  if (e < NE) {
    const int d = dstIdx[e];
    const int pos = offs[d] + atomicAdd(&cursor[d], 1);
    eperm[pos] = e;
    sdst[pos] = d;
    ssrc[pos] = srcIdx[e];
  }
}

// ---------------------------------------------------------------------------
// Sort+convert ea: eab[pos][k] = bf16(ea[eperm[pos]][k]).  One wave per
// sorted row (1 KB coalesced read, 512 B coalesced write); pure streaming.
// After this, the edge GEMM's A rows are CONSECUTIVE and bf16 -> m97-style
// global_load_lds staging with linear LDS.
// ---------------------------------------------------------------------------
__global__ __launch_bounds__(256) void k_sortcvt(
    const float* __restrict__ ea, const int* __restrict__ eperm,
    bf16_t* __restrict__ eab) {
  const int lane = threadIdx.x & 63, wv = threadIdx.x >> 6;
  const int stride = gridDim.x * 4;
  for (int pos = blockIdx.x * 4 + wv; pos < NE; pos += stride) {
    const float* src = ea + (size_t)eperm[pos] * NC + lane * 4;
    const f32x4 v = *(const f32x4*)src;
    bf16x4 o;
#pragma unroll
    for (int j = 0; j < 4; j++) o[j] = (bf16_t)v[j];
    *(bf16x4*)&eab[(size_t)pos * NC + lane * 4] = o;
  }
}

// ---------------------------------------------------------------------------
// Node-level PQ GEMM: [P | Q] = xb @ w1abt^T.  M=10000, K=256, N=1024.
// ---------------------------------------------------------------------------
__global__ __launch_bounds__(256) void k_pq(
    const bf16_t* __restrict__ xb,     // [NN][256]
    const bf16_t* __restrict__ w1abt,  // [1024][256]
    const float*  __restrict__ b1,
    float*        __restrict__ P,      // [NN][512] fp32 (= x@W1a' + b1)
    bf16_t*       __restrict__ Qb) {   // [NN][512] bf16 (= x@W1b)
  __shared__ bf16_t sA[128 * 64];
  __shared__ bf16_t sB[128 * 64];

  const int tid = threadIdx.x;
  const int cb = blockIdx.x & 7, rblk = blockIdx.x >> 3;
  const int r0 = rblk * 128, n0 = cb * 128;
  const int lane = tid & 63, wid = tid >> 6;
  const int mbase = (wid >> 1) * 64, nbase = (wid & 1) * 64;
  const int lr = lane >> 3, ls = lane & 7, slog = ls ^ lr;
  const int g = lane >> 4;

  f32x4 acc[4][4];
#pragma unroll
  for (int mi = 0; mi < 4; mi++)
#pragma unroll
    for (int ni = 0; ni < 4; ni++) acc[mi][ni] = (f32x4){0.f, 0.f, 0.f, 0.f};

  for (int kb = 0; kb < K1; kb += 64) {
#pragma unroll
    for (int i = 0; i < 4; i++) {
      const int row = wid * 32 + i * 8;          // wave-uniform
      int grow = r0 + row + lr;                  // per-lane source row
      if (grow > NN - 1) grow = NN - 1;          // clamp (guarded on write)
      gload_lds16(xb + (size_t)grow * NC + kb + slog * 8, &sA[row * 64]);
      gload_lds16(w1abt + (size_t)(n0 + permB(row + lr)) * K1 + kb + slog * 8,
                  &sB[row * 64]);
    }
    __syncthreads();
#pragma unroll
    for (int kk = 0; kk < 2; kk++) {
      const int sl = kk * 4 + g;
      bf16x8 av[4], bv[4];
#pragma unroll
      for (int mi = 0; mi < 4; mi++) {
        const int rA = mbase + mi * 16 + (lane & 15);
        av[mi] = *(const bf16x8*)&sA[rA * 64 + ((sl ^ (rA & 7)) * 8)];
      }
#pragma unroll
      for (int ni = 0; ni < 4; ni++) {
        const int rB = nbase + ni * 16 + (lane & 15);
        bv[ni] = *(const bf16x8*)&sB[rB * 64 + ((sl ^ (rB & 7)) * 8)];
      }
#pragma unroll
      for (int mi = 0; mi < 4; mi++)
#pragma unroll
        for (int ni = 0; ni < 4; ni++)
          acc[mi][ni] = __builtin_amdgcn_mfma_f32_16x16x32_bf16(av[mi], bv[ni], acc[mi][ni], 0, 0, 0);
    }
    __syncthreads();
  }

  const int col0 = n0 + nbase + (lane & 15) * 4;
  f32x4 b1v = {0.f, 0.f, 0.f, 0.f};
  if (col0 < OC) b1v = *(const f32x4*)&b1[col0];
#pragma unroll
  for (int mi = 0; mi < 4; mi++) {
#pragma unroll
    for (int q = 0; q < 4; q++) {
      const int grow = r0 + mbase + mi * 16 + g * 4 + q;
      if (grow < NN) {
        if (col0 < OC) {
          f32x4 v;
#pragma unroll
          for (int j = 0; j < 4; j++) v[j] = acc[mi][j][q] + b1v[j];
          *(f32x4*)&P[(size_t)grow * OC + col0] = v;
        } else {
          bf16x4 v;
#pragma unroll
          for (int j = 0; j < 4; j++) v[j] = (bf16_t)acc[mi][j][q];
          *(bf16x4*)&Qb[(size_t)grow * OC + (col0 - OC)] = v;
        }
      }
    }
  }
}

// ---------------------------------------------------------------------------
// Edge GEMM v7: R = eab @ W1c (K=256), eab pre-sorted+bf16.  BM=128 edges,
// BN=128 cols, 4 waves, R7 pipeline, BOTH tiles staged via global_load_lds
// (4+4 per wave per K-step, XOR source swizzle, linear LDS).  No VGPR
// round-trip, no cvt, no ds_writes in the hot loop.  P/Q epilogue gathers
// prefetched before the K-loop.  Fused segreduce epilogue (R7 verbatim).
// ---------------------------------------------------------------------------
__global__ __launch_bounds__(256, 2) void k_edge_gemm(
    const bf16_t* __restrict__ eab,    // [NE][256] bf16, dst-sorted order
    const bf16_t* __restrict__ w1ct,   // [512][256] bf16
    const float*  __restrict__ P,      // [NN][512] f32 (b1 folded)
    const bf16_t* __restrict__ Qb,     // [NN][512] bf16
    const int*    __restrict__ sdst,
    const int*    __restrict__ ssrc,
    float*        __restrict__ agg) {  // [NN][512] f32
  __shared__ bf16_t sM[2][128 * 64];   // eab tile, double-buffered (32 KB)
  __shared__ bf16_t sW[2][128 * 64];   // W1c tile, double-buffered (32 KB)
  __shared__ int sDst[128];
  __shared__ int sSrc[128];

  const int bid = (blockIdx.x & 7) * 1250 + (blockIdx.x >> 3);  // XCD swizzle
  const int cb = bid & 3, eblk = bid >> 2;
  const int e0 = eblk * 128, n0 = cb * 128;

  const int tid = threadIdx.x;
  if (tid < 128) { sDst[tid] = sdst[e0 + tid]; sSrc[tid] = ssrc[e0 + tid]; }
  __syncthreads();

  const int lane = tid & 63, wid = tid >> 6;
  const int mbase = (wid >> 1) * 64, nbase = (wid & 1) * 64;
  const int g = lane >> 4, r = lane & 15;
  const int lr = lane >> 3, ls = lane & 7, slog = ls ^ lr;

#define STAGE(kt, b)                                                          \
  _Pragma("unroll") for (int i = 0; i < 4; i++) {                             \
    const int rowb = wid * 32 + i * 8;  /* wave-uniform base */               \
    gload_lds16(eab + (size_t)(e0 + rowb + lr) * K1 + (kt)*64 + slog * 8,     \
                &sM[b][rowb * 64]);                                           \
    gload_lds16(w1ct + (size_t)(n0 + permB(rowb + lr)) * K1 + (kt)*64 + slog * 8, \
                &sW[b][rowb * 64]);                                           \
  }

  // prologue: stage K-step 0; prefetch P/Q gathers (consumed in epilogue)
  STAGE(0, 0);

  const int col0 = n0 + nbase + r * 4;
  f32x4  Pp[4][4];
  bf16x4 Qp[4][4];
#pragma unroll
  for (int mi = 0; mi < 4; mi++) {
    const int rbase = mbase + mi * 16 + g * 4;
#pragma unroll
    for (int q = 0; q < 4; q++) {
      Pp[mi][q] = *(const f32x4*)&P[(size_t)sDst[rbase + q] * OC + col0];
      Qp[mi][q] = *(const bf16x4*)&Qb[(size_t)sSrc[rbase + q] * OC + col0];
    }
  }

  f32x4 acc[4][4];
#pragma unroll
  for (int mi = 0; mi < 4; mi++)
#pragma unroll
    for (int ni = 0; ni < 4; ni++) acc[mi][ni] = (f32x4){0.f, 0.f, 0.f, 0.f};

  // pipelined K-loop: 4 steps, one barrier per step
#pragma unroll
  for (int t = 0; t < 4; t++) {
    const int b = t & 1;
    __syncthreads();                     // buf b staged for step t
    if (t < 3) STAGE(t + 1, b ^ 1);      // in flight during MFMA
#pragma unroll
    for (int kk = 0; kk < 2; kk++) {
      const int sl = kk * 4 + g;
      bf16x8 av[4], bv[4];
#pragma unroll
      for (int mi = 0; mi < 4; mi++) {
        const int rA = mbase + mi * 16 + r;
        av[mi] = *(const bf16x8*)&sM[b][rA * 64 + ((sl ^ (rA & 7)) * 8)];
      }
#pragma unroll
      for (int ni = 0; ni < 4; ni++) {
        const int rB = nbase + ni * 16 + r;
        bv[ni] = *(const bf16x8*)&sW[b][rB * 64 + ((sl ^ (rB & 7)) * 8)];
      }
#pragma unroll
      for (int mi = 0; mi < 4; mi++)
#pragma unroll
        for (int ni = 0; ni < 4; ni++)
          acc[mi][ni] = __builtin_amdgcn_mfma_f32_16x16x32_bf16(av[mi], bv[ni], acc[mi][ni], 0, 0, 0);
    }
  }
#undef STAGE

  // ---- epilogue: relu(acc + P[dst] + Q[src]) -> segmented reduce ----
#pragma unroll
  for (int mi = 0; mi < 4; mi++) {
    const int rbase = mbase + mi * 16 + g * 4;
    const int d0 = sDst[rbase],     d1 = sDst[rbase + 1];
    const int d2 = sDst[rbase + 2], d3 = sDst[rbase + 3];
    const int headId = d0, tailId = d3;
    const bool b1q = (d1 != d0), b2q = (d2 != d1), b3q = (d3 != d2);
    const bool seen = b1q | b2q | b3q;
    bool match[3];
#pragma unroll
    for (int j = 0; j < 3; j++) {
      const int tIdj = __shfl(tailId, (lane & 15) | (j << 4));
      match[j] = (j < g) && (tIdj == headId);
    }
    const int nextHead = __shfl(headId, (lane + 16) & 63);
    const bool endsHere = (g == 3) || (nextHead != tailId);

    f32x4 v0, v1, v2, v3;
#pragma unroll
    for (int j = 0; j < 4; j++) {
      v0[j] = fmaxf(acc[mi][j][0] + Pp[mi][0][j] + (float)Qp[mi][0][j], 0.f);
      v1[j] = fmaxf(acc[mi][j][1] + Pp[mi][1][j] + (float)Qp[mi][1][j], 0.f);
      v2[j] = fmaxf(acc[mi][j][2] + Pp[mi][2][j] + (float)Qp[mi][2][j], 0.f);
      v3[j] = fmaxf(acc[mi][j][3] + Pp[mi][3][j] + (float)Qp[mi][3][j], 0.f);
    }

    // quad walk: head run, interior flushes, tail run (element-wise f32x4)
    f32x4 head = {0.f, 0.f, 0.f, 0.f}, run = v0;
    bool first = true;
    if (b1q) { head = run; first = false; run = v1; } else run += v1;
    if (b2q) {
      if (first) { head = run; first = false; }
      else {
        float* base = agg + (size_t)d1 * OC + col0;
#pragma unroll
        for (int j = 0; j < 4; j++) if (run[j] != 0.f) atomicAdd(base + j, run[j]);
      }
      run = v2;
    } else run += v2;
    if (b3q) {
      if (first) { head = run; first = false; }
      else {
        float* base = agg + (size_t)d2 * OC + col0;
#pragma unroll
        for (int j = 0; j < 4; j++) if (run[j] != 0.f) atomicAdd(base + j, run[j]);
      }
      run = v3;
    } else run += v3;
    const f32x4 tailSum = run;

    f32x4 inc = {0.f, 0.f, 0.f, 0.f};
#pragma unroll
    for (int jg = 0; jg < 3; jg++) {
      f32x4 ts;
#pragma unroll
      for (int c = 0; c < 4; c++) ts[c] = __shfl(tailSum[c], (lane & 15) | (jg << 4));
      if (match[jg]) inc += ts;
    }
    if (seen) {
      float* base = agg + (size_t)headId * OC + col0;
#pragma unroll
      for (int j = 0; j < 4; j++) {
        const float h = head[j] + inc[j];
        if (h != 0.f) atomicAdd(base + j, h);
      }
    }
    if (endsHere) {
      float* base = agg + (size_t)tailId * OC + col0;
#pragma unroll
      for (int j = 0; j < 4; j++) {
        const float t2 = tailSum[j] + (seen ? 0.f : inc[j]);
        if (t2 != 0.f) atomicAdd(base + j, t2);
      }
    }
  }
}

// ---------------------------------------------------------------------------
// Node GEMM: out = agg @ W2 + deg * b2   (10000x512 @ 512x512)
// ---------------------------------------------------------------------------
__global__ __launch_bounds__(256) void k_node_gemm(
    const float*  __restrict__ agg,
    const bf16_t* __restrict__ w2t,
    const float*  __restrict__ b2,
    const int*    __restrict__ deg,
    float*        __restrict__ out) {
  __shared__ bf16_t sM[128 * 72];
  __shared__ bf16_t sW[128 * 72];

  const int tid  = threadIdx.x;
  const int bid  = blockIdx.x;
  const int cb   = bid & 3;
  const int rblk = bid >> 2;
  const int r0   = rblk * 128;
  const int n0   = cb * 128;

  const int lane  = tid & 63, wid = tid >> 6;
  const int mbase = (wid >> 1) * 64, nbase = (wid & 1) * 64;
  const int se = tid >> 1;
  const int sk = (tid & 1) * 32;
  const int arow  = r0 + se;
  const bool rowok = arow < NN;

  f32x4 acc[4][4];
#pragma unroll
  for (int mi = 0; mi < 4; mi++)
#pragma unroll
    for (int ni = 0; ni < 4; ni++) acc[mi][ni] = (f32x4){0.f, 0.f, 0.f, 0.f};

  for (int kb = 0; kb < OC; kb += 64) {
    {
      bf16x8* dst = (bf16x8*)&sM[se * 72 + sk];
      if (rowok) {
        const float* pf = agg + (size_t)arow * OC + kb + sk;
        f32x4 f[8];
#pragma unroll
        for (int i = 0; i < 8; i++) f[i] = *(const f32x4*)(pf + i * 4);
#pragma unroll
        for (int i = 0; i < 4; i++) {
          bf16x8 v;
#pragma unroll
          for (int j = 0; j < 4; j++) {
            v[j]     = (bf16_t)f[2 * i][j];
            v[4 + j] = (bf16_t)f[2 * i + 1][j];
          }
          dst[i] = v;
        }
      } else {
        bf16x8 z = {};
        dst[0] = z; dst[1] = z; dst[2] = z; dst[3] = z;
      }
    }
    {
      const bf16_t* pw = w2t + (size_t)(n0 + permB(se)) * OC + kb + sk;
      bf16x8* dst = (bf16x8*)&sW[se * 72 + sk];
      dst[0] = *(const bf16x8*)(pw);
      dst[1] = *(const bf16x8*)(pw + 8);
      dst[2] = *(const bf16x8*)(pw + 16);
      dst[3] = *(const bf16x8*)(pw + 24);
    }
    __syncthreads();
#pragma unroll
    for (int kk = 0; kk < 2; kk++) {
      const int krd = kk * 32 + (lane >> 4) * 8;
      bf16x8 av[4], bv[4];
#pragma unroll
      for (int mi = 0; mi < 4; mi++)
        av[mi] = *(const bf16x8*)&sM[(mbase + mi * 16 + (lane & 15)) * 72 + krd];
#pragma unroll
      for (int ni = 0; ni < 4; ni++)
        bv[ni] = *(const bf16x8*)&sW[(nbase + ni * 16 + (lane & 15)) * 72 + krd];
#pragma unroll
      for (int mi = 0; mi < 4; mi++)
#pragma unroll
        for (int ni = 0; ni < 4; ni++)
          acc[mi][ni] = __builtin_amdgcn_mfma_f32_16x16x32_bf16(av[mi], bv[ni], acc[mi][ni], 0, 0, 0);
    }
    __syncthreads();
  }

  const int col0 = n0 + nbase + (lane & 15) * 4;
  const f32x4 b2v = *(const f32x4*)&b2[col0];
  const int g = lane >> 4;
#pragma unroll
  for (int mi = 0; mi < 4; mi++) {
#pragma unroll
    for (int q = 0; q < 4; q++) {
      const int row = r0 + mbase + mi * 16 + g * 4 + q;
      if (row < NN) {
        const float dg = (float)deg[row];
        f32x4 v;
#pragma unroll
        for (int j = 0; j < 4; j++) v[j] = acc[mi][j][q] + b2v[j] * dg;
        *(f32x4*)&out[(size_t)row * OC + col0] = v;
      }
    }
  }
}

// ---------------------------------------------------------------------------
// BatchNorm: stats, finalize, apply(+relu).
// ---------------------------------------------------------------------------
__global__ void k_bn_stats(const float* __restrict__ out, float* __restrict__ sums) {
  const int c = threadIdx.x;
  float s1 = 0.f, q1 = 0.f, s2 = 0.f, q2 = 0.f;
  for (int n = blockIdx.x; n < NN; n += gridDim.x) {
    const float* row = out + (size_t)n * OC;
    const float v1 = row[c], v2 = row[c + 256];
    s1 += v1; q1 += v1 * v1;
    s2 += v2; q2 += v2 * v2;
  }
  atomicAdd(&sums[c], s1);        atomicAdd(&sums[OC + c], q1);
  atomicAdd(&sums[c + 256], s2);  atomicAdd(&sums[OC + c + 256], q2);
}

__global__ void k_bn_finalize(const float* __restrict__ sums,
                              const float* __restrict__ gamma,
                              const float* __restrict__ beta,
                              float* __restrict__ scale,
                              float* __restrict__ shift) {
  const int c = threadIdx.x;
  const float mean = sums[c] * (1.0f / NN);
  const float var  = sums[OC + c] * (1.0f / NN) - mean * mean;
  const float r    = rsqrtf(var + 1e-5f);
  const float sc   = r * gamma[c];
  scale[c] = sc;
  shift[c] = beta[c] - mean * sc;
}

__global__ void k_bn_apply(float* __restrict__ out,
                           const float* __restrict__ scale,
                           const float* __restrict__ shift) {
  const int i = blockIdx.x * blockDim.x + threadIdx.x;
  f32x4 v = *((const f32x4*)out + i);
  const int c = (i & 127) << 2;
  f32x4 r;
#pragma unroll
  for (int j = 0; j < 4; j++) r[j] = fmaxf(v[j] * scale[c + j] + shift[c + j], 0.0f);
  *((f32x4*)out + i) = r;
}

// ---------------------------------------------------------------------------
extern "C" void kernel_launch(void* const* d_in, const int* in_sizes, int n_in,
                              void* d_out, int out_size, void* d_ws, size_t ws_size,
                              hipStream_t stream) {
  const float* x     = (const float*)d_in[0];
  const int*   ei    = (const int*)d_in[1];
  const float* ea    = (const float*)d_in[2];
  const float* W1    = (const float*)d_in[3];
  const float* b1    = (const float*)d_in[4];
  const float* W2    = (const float*)d_in[5];
  const float* b2    = (const float*)d_in[6];
  const float* gamma = (const float*)d_in[7];
  const float* beta  = (const float*)d_in[8];
  float* out = (float*)d_out;

  char* ws = (char*)d_ws;
  float*  agg    = (float*)(ws);                    // 20,480,000 B
  float*  P      = (float*)(ws + 20480000);         // 20,480,000 B
  bf16_t* Qb     = (bf16_t*)(ws + 40960000);        // 10,240,000 B
  bf16_t* xb     = (bf16_t*)(ws + 51200000);        //  5,120,000 B
  bf16_t* w1abt  = (bf16_t*)(ws + 56320000);        //    524,288 B
  bf16_t* w1ct   = (bf16_t*)(ws + 56844288);        //    262,144 B
  bf16_t* w2t    = (bf16_t*)(ws + 57106432);        //    524,288 B
  int*    deg    = (int*)(ws + 57630720);           //     40,000 B
  int*    offs   = (int*)(ws + 57670720);           //     40,000 B
  int*    cursor = (int*)(ws + 57710720);           //     40,000 B
  float*  sums   = (float*)(ws + 57750720);         //      4,096 B
  float*  scale  = (float*)(ws + 57754816);         //      2,048 B
  float*  shift  = (float*)(ws + 57756864);         //      2,048 B
  int*    eperm  = (int*)(ws + 57758912);           //  1,280,000 B
  int*    sdst   = (int*)(ws + 59038912);           //  1,280,000 B
  int*    ssrc   = (int*)(ws + 60318912);           //  1,280,000 B
  bf16_t* eab    = (bf16_t*)(ws + 61598912);        // 163,840,000 B (ws >= 389MB proven R12)

  const int* srcIdx = ei;
  const int* dstIdx = ei + NE;

  k_prep<<<4096, 256, 0, stream>>>(x, W1, W2, xb, w1abt, w1ct, w2t, agg, deg, cursor, sums);
  k_deg<<<(NE + 255) / 256, 256, 0, stream>>>(dstIdx, deg);
  k_scan<<<1, 256, 0, stream>>>(deg, offs);
  k_scatter<<<(NE + 255) / 256, 256, 0, stream>>>(srcIdx, dstIdx, offs, cursor,
                                                  eperm, sdst, ssrc);
  k_sortcvt<<<2048, 256, 0, stream>>>(ea, eperm, eab);
  k_pq<<<((NN + 127) / 128) * 8, 256, 0, stream>>>(xb, w1abt, b1, P, Qb);
  k_edge_gemm<<<(NE / 128) * 4, 256, 0, stream>>>(eab, w1ct, P, Qb, sdst, ssrc, agg);
  k_node_gemm<<<((NN + 127) / 128) * 4, 256, 0, stream>>>(agg, w2t, b2, deg, out);
  k_bn_stats<<<256, 256, 0, stream>>>(out, sums);
  k_bn_finalize<<<1, 512, 0, stream>>>(sums, gamma, beta, scale, shift);
  k_bn_apply<<<(NN * OC / 4 + 255) / 256, 256, 0, stream>>>(out, scale, shift);
}

// Round 14
// 499.981 us; speedup vs baseline: 1.1452x; 1.1429x over previous
//
#include <hip/hip_runtime.h>
#include <hip/hip_bf16.h>
#include <cstdint>

// Problem constants (fixed by the reference)
#define NN 10000      // nodes
#define NE 320000     // edges
#define NC 256        // node channels
#define OC 512        // out channels
#define K1 256        // K for edge gemm (ea) and pq gemm (x)

typedef __bf16 bf16_t;
typedef bf16_t bf16x8 __attribute__((ext_vector_type(8)));
typedef bf16_t bf16x4 __attribute__((ext_vector_type(4)));
typedef float  f32x4  __attribute__((ext_vector_type(4)));

// async global->LDS, 16B per lane; LDS dest = wave-uniform base + lane*16
__device__ __forceinline__ void gload_lds16(const void* g, void* l) {
  __builtin_amdgcn_global_load_lds(
      (const __attribute__((address_space(1))) unsigned int*)g,
      (__attribute__((address_space(3))) unsigned int*)l, 16, 0, 0);
}

// B-side column interleave: LDS tile row R holds the weight row for logical
// column (R&~63) + (R&15)*4 + ((R>>4)&3)  ->  each lane's 4 MFMA fragments
// cover 4 CONSECUTIVE output columns (vector epilogue).
__device__ __forceinline__ int permB(int R) {
  return (R & ~63) + ((R & 15) << 2) + ((R >> 4) & 3);
}

// ---------------------------------------------------------------------------
// Prep: zero agg/deg/cursor/sums, xb=bf16(x), build transposed bf16 weights.
// ---------------------------------------------------------------------------
__global__ void k_prep(const float* __restrict__ x,
                       const float* __restrict__ W1,
                       const float* __restrict__ W2,
                       bf16_t* __restrict__ xb,
                       bf16_t* __restrict__ w1abt,
                       bf16_t* __restrict__ w1ct,
                       bf16_t* __restrict__ w2t,
                       float* __restrict__ agg,
                       int* __restrict__ deg,
                       int* __restrict__ cursor,
                       float* __restrict__ sums) {
  const int stride = gridDim.x * blockDim.x;
  for (int i = blockIdx.x * blockDim.x + threadIdx.x; i < NN * OC; i += stride) {
    agg[i] = 0.0f;
    if (i < NN * NC) xb[i] = (bf16_t)x[i];
    if (i < 1024 * K1) {
      const int n = i >> 8, k = i & 255;
      float w;
      if (n < OC) w = W1[(size_t)k * OC + n] - W1[(size_t)(k + NC) * OC + n];
      else        w = W1[(size_t)(k + NC) * OC + (n - OC)];
      w1abt[i] = (bf16_t)w;
    }
    if (i < OC * K1) {
      const int n = i >> 8, k = i & 255;
      w1ct[i] = (bf16_t)W1[(size_t)(512 + k) * OC + n];
    }
    if (i < OC * OC) {
      const int n = i >> 9, k = i & 511;
      w2t[i] = (bf16_t)W2[(size_t)k * OC + n];
    }
    if (i < NN) { deg[i] = 0; cursor[i] = 0; }
    if (i < 1024) sums[i] = 0.0f;
  }
}

__global__ void k_deg(const int* __restrict__ dstIdx, int* __restrict__ deg) {
  const int i = blockIdx.x * blockDim.x + threadIdx.x;
  if (i < NE) atomicAdd(&deg[dstIdx[i]], 1);
}

// Single-block exclusive prefix sum over NN bins.
__global__ void k_scan(const int* __restrict__ deg, int* __restrict__ offs) {
  __shared__ int carry;
  __shared__ int wsum[4];
  if (threadIdx.x == 0) carry = 0;
  __syncthreads();
  const int lane = threadIdx.x & 63, w = threadIdx.x >> 6;
  for (int base = 0; base < NN; base += 256) {
    const int i = base + threadIdx.x;
    const int v = (i < NN) ? deg[i] : 0;
    int s = v;
#pragma unroll
    for (int d = 1; d < 64; d <<= 1) { int t = __shfl_up(s, d); if (lane >= d) s += t; }
    if (lane == 63) wsum[w] = s;
    __syncthreads();
    int woff = 0;
    for (int j = 0; j < w; j++) woff += wsum[j];
    const int incl = s + woff + carry;
    if (i < NN) offs[i] = incl - v;  // exclusive
    __syncthreads();
    if (threadIdx.x == 255) carry = incl;
    __syncthreads();
  }
}

// Counting-sort scatter: edges grouped by dst.
__global__ void k_scatter(const int* __restrict__ srcIdx, const int* __restrict__ dstIdx,
                          const int* __restrict__ offs, int* __restrict__ cursor,
                          int* __restrict__ eperm, int* __restrict__ sdst,
                          int* __restrict__ ssrc) {
  const int e = blockIdx.x * blockDim.x + threadIdx.x;
  if (e < NE) {
    const int d = dstIdx[e];
    const int pos = offs[d] + atomicAdd(&cursor[d], 1);
    eperm[pos] = e;
    sdst[pos] = d;
    ssrc[pos] = srcIdx[e];
  }
}

// ---------------------------------------------------------------------------
// Node-level PQ GEMM: [P | Q] = xb @ w1abt^T.  M=10000, K=256, N=1024.
// ---------------------------------------------------------------------------
__global__ __launch_bounds__(256) void k_pq(
    const bf16_t* __restrict__ xb,     // [NN][256]
    const bf16_t* __restrict__ w1abt,  // [1024][256]
    const float*  __restrict__ b1,
    float*        __restrict__ P,      // [NN][512] fp32 (= x@W1a' + b1)
    bf16_t*       __restrict__ Qb) {   // [NN][512] bf16 (= x@W1b)
  __shared__ bf16_t sA[128 * 64];
  __shared__ bf16_t sB[128 * 64];

  const int tid = threadIdx.x;
  const int cb = blockIdx.x & 7, rblk = blockIdx.x >> 3;
  const int r0 = rblk * 128, n0 = cb * 128;
  const int lane = tid & 63, wid = tid >> 6;
  const int mbase = (wid >> 1) * 64, nbase = (wid & 1) * 64;
  const int lr = lane >> 3, ls = lane & 7, slog = ls ^ lr;
  const int g = lane >> 4;

  f32x4 acc[4][4];
#pragma unroll
  for (int mi = 0; mi < 4; mi++)
#pragma unroll
    for (int ni = 0; ni < 4; ni++) acc[mi][ni] = (f32x4){0.f, 0.f, 0.f, 0.f};

  for (int kb = 0; kb < K1; kb += 64) {
#pragma unroll
    for (int i = 0; i < 4; i++) {
      const int row = wid * 32 + i * 8;          // wave-uniform
      int grow = r0 + row + lr;                  // per-lane source row
      if (grow > NN - 1) grow = NN - 1;          // clamp (guarded on write)
      gload_lds16(xb + (size_t)grow * NC + kb + slog * 8, &sA[row * 64]);
      gload_lds16(w1abt + (size_t)(n0 + permB(row + lr)) * K1 + kb + slog * 8,
                  &sB[row * 64]);
    }
    __syncthreads();
#pragma unroll
    for (int kk = 0; kk < 2; kk++) {
      const int sl = kk * 4 + g;
      bf16x8 av[4], bv[4];
#pragma unroll
      for (int mi = 0; mi < 4; mi++) {
        const int rA = mbase + mi * 16 + (lane & 15);
        av[mi] = *(const bf16x8*)&sA[rA * 64 + ((sl ^ (rA & 7)) * 8)];
      }
#pragma unroll
      for (int ni = 0; ni < 4; ni++) {
        const int rB = nbase + ni * 16 + (lane & 15);
        bv[ni] = *(const bf16x8*)&sB[rB * 64 + ((sl ^ (rB & 7)) * 8)];
      }
#pragma unroll
      for (int mi = 0; mi < 4; mi++)
#pragma unroll
        for (int ni = 0; ni < 4; ni++)
          acc[mi][ni] = __builtin_amdgcn_mfma_f32_16x16x32_bf16(av[mi], bv[ni], acc[mi][ni], 0, 0, 0);
    }
    __syncthreads();
  }

  const int col0 = n0 + nbase + (lane & 15) * 4;
  f32x4 b1v = {0.f, 0.f, 0.f, 0.f};
  if (col0 < OC) b1v = *(const f32x4*)&b1[col0];
#pragma unroll
  for (int mi = 0; mi < 4; mi++) {
#pragma unroll
    for (int q = 0; q < 4; q++) {
      const int grow = r0 + mbase + mi * 16 + g * 4 + q;
      if (grow < NN) {
        if (col0 < OC) {
          f32x4 v;
#pragma unroll
          for (int j = 0; j < 4; j++) v[j] = acc[mi][j][q] + b1v[j];
          *(f32x4*)&P[(size_t)grow * OC + col0] = v;
        } else {
          bf16x4 v;
#pragma unroll
          for (int j = 0; j < 4; j++) v[j] = (bf16_t)acc[mi][j][q];
          *(bf16x4*)&Qb[(size_t)grow * OC + (col0 - OC)] = v;
        }
      }
    }
  }
}

// ---------------------------------------------------------------------------
// Edge GEMM (R7 champion, verbatim): R = ea @ W1c (K=256).  BM=128, BN=128,
// 4 waves, dbuf both tiles, 1 barrier/K-step, P/Q prologue prefetch,
// fused segreduce epilogue, XCD chunk swizzle.
// ---------------------------------------------------------------------------
__global__ __launch_bounds__(256, 2) void k_edge_gemm(
    const float*  __restrict__ ea,
    const bf16_t* __restrict__ w1ct,
    const float*  __restrict__ P,
    const bf16_t* __restrict__ Qb,
    const int*    __restrict__ eperm,
    const int*    __restrict__ sdst,
    const int*    __restrict__ ssrc,
    float*        __restrict__ agg) {
  __shared__ bf16_t sM[2][128 * 64];
  __shared__ bf16_t sW[2][128 * 64];
  __shared__ int sDst[128];
  __shared__ int sSrc[128];
  __shared__ int sE[128];

  const int bid = (blockIdx.x & 7) * 1250 + (blockIdx.x >> 3);
  const int cb = bid & 3, eblk = bid >> 2;
  const int e0 = eblk * 128, n0 = cb * 128;

  const int tid = threadIdx.x;
  if (tid < 128) {
    sDst[tid] = sdst[e0 + tid];
    sSrc[tid] = ssrc[e0 + tid];
    sE[tid]   = eperm[e0 + tid];
  }
  __syncthreads();

  const int lane = tid & 63, wid = tid >> 6;
  const int mbase = (wid >> 1) * 64, nbase = (wid & 1) * 64;
  const int g = lane >> 4, r = lane & 15;
  const int lr = lane >> 3, ls = lane & 7, slogW = ls ^ lr;
  const int mrow = tid >> 1, qd = tid & 1;
  const int msw = mrow & 7;
  const float* eaRow = ea + (size_t)sE[mrow] * NC;

#define STAGE_W(kt, b)                                                        \
  _Pragma("unroll") for (int i = 0; i < 4; i++) {                             \
    const int rowb = wid * 32 + i * 8;                                        \
    gload_lds16(w1ct + (size_t)(n0 + permB(rowb + lr)) * K1 + (kt)*64 + slogW * 8, \
                &sW[b][rowb * 64]);                                           \
  }
#define LOAD_A(kt)                                                            \
  _Pragma("unroll") for (int j = 0; j < 8; j++)                               \
      a[j] = *(const f32x4*)(eaRow + (kt)*64 + qd * 32 + j * 4);
#define WRITE_M(b)                                                            \
  _Pragma("unroll") for (int tt = 0; tt < 4; tt++) {                          \
    const int slot = qd * 4 + tt;                                             \
    bf16x8 v;                                                                 \
    _Pragma("unroll") for (int jj = 0; jj < 4; jj++) {                        \
      v[jj] = (bf16_t)a[tt * 2][jj];                                          \
      v[4 + jj] = (bf16_t)a[tt * 2 + 1][jj];                                  \
    }                                                                         \
    *(bf16x8*)&sM[b][mrow * 64 + ((slot ^ msw) * 8)] = v;                     \
  }

  f32x4 a[8];
  STAGE_W(0, 0);
  LOAD_A(0);

  const int col0 = n0 + nbase + r * 4;
  f32x4  Pp[4][4];
  bf16x4 Qp[4][4];
#pragma unroll
  for (int mi = 0; mi < 4; mi++) {
    const int rbase = mbase + mi * 16 + g * 4;
#pragma unroll
    for (int q = 0; q < 4; q++) {
      Pp[mi][q] = *(const f32x4*)&P[(size_t)sDst[rbase + q] * OC + col0];
      Qp[mi][q] = *(const bf16x4*)&Qb[(size_t)sSrc[rbase + q] * OC + col0];
    }
  }

  WRITE_M(0);

  f32x4 acc[4][4];
#pragma unroll
  for (int mi = 0; mi < 4; mi++)
#pragma unroll
    for (int ni = 0; ni < 4; ni++) acc[mi][ni] = (f32x4){0.f, 0.f, 0.f, 0.f};

#pragma unroll
  for (int t = 0; t < 4; t++) {
    const int b = t & 1;
    __syncthreads();
    if (t < 3) { STAGE_W(t + 1, b ^ 1); LOAD_A(t + 1); }
#pragma unroll
    for (int kk = 0; kk < 2; kk++) {
      const int sl = kk * 4 + g;
      bf16x8 av[4], bv[4];
#pragma unroll
      for (int mi = 0; mi < 4; mi++) {
        const int rA = mbase + mi * 16 + r;
        av[mi] = *(const bf16x8*)&sM[b][rA * 64 + ((sl ^ (rA & 7)) * 8)];
      }
#pragma unroll
      for (int ni = 0; ni < 4; ni++) {
        const int rB = nbase + ni * 16 + r;
        bv[ni] = *(const bf16x8*)&sW[b][rB * 64 + ((sl ^ (rB & 7)) * 8)];
      }
#pragma unroll
      for (int mi = 0; mi < 4; mi++)
#pragma unroll
        for (int ni = 0; ni < 4; ni++)
          acc[mi][ni] = __builtin_amdgcn_mfma_f32_16x16x32_bf16(av[mi], bv[ni], acc[mi][ni], 0, 0, 0);
    }
    if (t < 3) { WRITE_M(b ^ 1); }
  }
#undef STAGE_W
#undef LOAD_A
#undef WRITE_M

#pragma unroll
  for (int mi = 0; mi < 4; mi++) {
    const int rbase = mbase + mi * 16 + g * 4;
    const int d0 = sDst[rbase],     d1 = sDst[rbase + 1];
    const int d2 = sDst[rbase + 2], d3 = sDst[rbase + 3];
    const int headId = d0, tailId = d3;
    const bool b1q = (d1 != d0), b2q = (d2 != d1), b3q = (d3 != d2);
    const bool seen = b1q | b2q | b3q;
    bool match[3];
#pragma unroll
    for (int j = 0; j < 3; j++) {
      const int tIdj = __shfl(tailId, (lane & 15) | (j << 4));
      match[j] = (j < g) && (tIdj == headId);
    }
    const int nextHead = __shfl(headId, (lane + 16) & 63);
    const bool endsHere = (g == 3) || (nextHead != tailId);

    f32x4 v0, v1, v2, v3;
#pragma unroll
    for (int j = 0; j < 4; j++) {
      v0[j] = fmaxf(acc[mi][j][0] + Pp[mi][0][j] + (float)Qp[mi][0][j], 0.f);
      v1[j] = fmaxf(acc[mi][j][1] + Pp[mi][1][j] + (float)Qp[mi][1][j], 0.f);
      v2[j] = fmaxf(acc[mi][j][2] + Pp[mi][2][j] + (float)Qp[mi][2][j], 0.f);
      v3[j] = fmaxf(acc[mi][j][3] + Pp[mi][3][j] + (float)Qp[mi][3][j], 0.f);
    }

    f32x4 head = {0.f, 0.f, 0.f, 0.f}, run = v0;
    bool first = true;
    if (b1q) { head = run; first = false; run = v1; } else run += v1;
    if (b2q) {
      if (first) { head = run; first = false; }
      else {
        float* base = agg + (size_t)d1 * OC + col0;
#pragma unroll
        for (int j = 0; j < 4; j++) if (run[j] != 0.f) atomicAdd(base + j, run[j]);
      }
      run = v2;
    } else run += v2;
    if (b3q) {
      if (first) { head = run; first = false; }
      else {
        float* base = agg + (size_t)d2 * OC + col0;
#pragma unroll
        for (int j = 0; j < 4; j++) if (run[j] != 0.f) atomicAdd(base + j, run[j]);
      }
      run = v3;
    } else run += v3;
    const f32x4 tailSum = run;

    f32x4 inc = {0.f, 0.f, 0.f, 0.f};
#pragma unroll
    for (int jg = 0; jg < 3; jg++) {
      f32x4 ts;
#pragma unroll
      for (int c = 0; c < 4; c++) ts[c] = __shfl(tailSum[c], (lane & 15) | (jg << 4));
      if (match[jg]) inc += ts;
    }
    if (seen) {
      float* base = agg + (size_t)headId * OC + col0;
#pragma unroll
      for (int j = 0; j < 4; j++) {
        const float h = head[j] + inc[j];
        if (h != 0.f) atomicAdd(base + j, h);
      }
    }
    if (endsHere) {
      float* base = agg + (size_t)tailId * OC + col0;
#pragma unroll
      for (int j = 0; j < 4; j++) {
        const float t2 = tailSum[j] + (seen ? 0.f : inc[j]);
        if (t2 != 0.f) atomicAdd(base + j, t2);
      }
    }
  }
}

// ---------------------------------------------------------------------------
// Node GEMM + fused BN stats: out = agg @ W2 + deg * b2, and per-channel
// (sum, sumsq) reduced in-register (shfl over g) -> atomicAdd into sums.
// ---------------------------------------------------------------------------
__global__ __launch_bounds__(256) void k_node_gemm(
    const float*  __restrict__ agg,
    const bf16_t* __restrict__ w2t,
    const float*  __restrict__ b2,
    const int*    __restrict__ deg,
    float*        __restrict__ out,
    float*        __restrict__ sums) {  // [2][512]: sum, sumsq
  __shared__ bf16_t sM[128 * 72];
  __shared__ bf16_t sW[128 * 72];

  const int tid  = threadIdx.x;
  const int bid  = blockIdx.x;
  const int cb   = bid & 3;
  const int rblk = bid >> 2;
  const int r0   = rblk * 128;
  const int n0   = cb * 128;

  const int lane  = tid & 63, wid = tid >> 6;
  const int mbase = (wid >> 1) * 64, nbase = (wid & 1) * 64;
  const int se = tid >> 1;
  const int sk = (tid & 1) * 32;
  const int arow  = r0 + se;
  const bool rowok = arow < NN;

  f32x4 acc[4][4];
#pragma unroll
  for (int mi = 0; mi < 4; mi++)
#pragma unroll
    for (int ni = 0; ni < 4; ni++) acc[mi][ni] = (f32x4){0.f, 0.f, 0.f, 0.f};

  for (int kb = 0; kb < OC; kb += 64) {
    {
      bf16x8* dst = (bf16x8*)&sM[se * 72 + sk];
      if (rowok) {
        const float* pf = agg + (size_t)arow * OC + kb + sk;
        f32x4 f[8];
#pragma unroll
        for (int i = 0; i < 8; i++) f[i] = *(const f32x4*)(pf + i * 4);
#pragma unroll
        for (int i = 0; i < 4; i++) {
          bf16x8 v;
#pragma unroll
          for (int j = 0; j < 4; j++) {
            v[j]     = (bf16_t)f[2 * i][j];
            v[4 + j] = (bf16_t)f[2 * i + 1][j];
          }
          dst[i] = v;
        }
      } else {
        bf16x8 z = {};
        dst[0] = z; dst[1] = z; dst[2] = z; dst[3] = z;
      }
    }
    {
      const bf16_t* pw = w2t + (size_t)(n0 + permB(se)) * OC + kb + sk;
      bf16x8* dst = (bf16x8*)&sW[se * 72 + sk];
      dst[0] = *(const bf16x8*)(pw);
      dst[1] = *(const bf16x8*)(pw + 8);
      dst[2] = *(const bf16x8*)(pw + 16);
      dst[3] = *(const bf16x8*)(pw + 24);
    }
    __syncthreads();
#pragma unroll
    for (int kk = 0; kk < 2; kk++) {
      const int krd = kk * 32 + (lane >> 4) * 8;
      bf16x8 av[4], bv[4];
#pragma unroll
      for (int mi = 0; mi < 4; mi++)
        av[mi] = *(const bf16x8*)&sM[(mbase + mi * 16 + (lane & 15)) * 72 + krd];
#pragma unroll
      for (int ni = 0; ni < 4; ni++)
        bv[ni] = *(const bf16x8*)&sW[(nbase + ni * 16 + (lane & 15)) * 72 + krd];
#pragma unroll
      for (int mi = 0; mi < 4; mi++)
#pragma unroll
        for (int ni = 0; ni < 4; ni++)
          acc[mi][ni] = __builtin_amdgcn_mfma_f32_16x16x32_bf16(av[mi], bv[ni], acc[mi][ni], 0, 0, 0);
    }
    __syncthreads();
  }

  const int col0 = n0 + nbase + (lane & 15) * 4;
  const f32x4 b2v = *(const f32x4*)&b2[col0];
  const int g = lane >> 4;
  f32x4 s1 = {0.f, 0.f, 0.f, 0.f}, s2 = {0.f, 0.f, 0.f, 0.f};
#pragma unroll
  for (int mi = 0; mi < 4; mi++) {
#pragma unroll
    for (int q = 0; q < 4; q++) {
      const int row = r0 + mbase + mi * 16 + g * 4 + q;
      if (row < NN) {
        const float dg = (float)deg[row];
        f32x4 v;
#pragma unroll
        for (int j = 0; j < 4; j++) {
          v[j] = acc[mi][j][q] + b2v[j] * dg;
          s1[j] += v[j];
          s2[j] += v[j] * v[j];
        }
        *(f32x4*)&out[(size_t)row * OC + col0] = v;
      }
    }
  }
  // reduce (s1,s2) over the g dimension (lanes differing in bits 4,5)
#pragma unroll
  for (int j = 0; j < 4; j++) {
    s1[j] += __shfl_xor(s1[j], 16);  s2[j] += __shfl_xor(s2[j], 16);
    s1[j] += __shfl_xor(s1[j], 32);  s2[j] += __shfl_xor(s2[j], 32);
  }
  if (g == 0) {
#pragma unroll
    for (int j = 0; j < 4; j++) {
      atomicAdd(&sums[col0 + j], s1[j]);
      atomicAdd(&sums[OC + col0 + j], s2[j]);
    }
  }
}

// ---------------------------------------------------------------------------
// BN apply (+relu), scale/shift computed inline from sums (L2-hot).
// ---------------------------------------------------------------------------
__global__ void k_bn_apply(float* __restrict__ out,
                           const float* __restrict__ sums,
                           const float* __restrict__ gamma,
                           const float* __restrict__ beta) {
  const int i = blockIdx.x * blockDim.x + threadIdx.x;  // float4 index
  f32x4 v = *((const f32x4*)out + i);
  const int c = (i & 127) << 2;
  const f32x4 sm = *(const f32x4*)&sums[c];
  const f32x4 sq = *(const f32x4*)&sums[OC + c];
  const f32x4 gm = *(const f32x4*)&gamma[c];
  const f32x4 bt = *(const f32x4*)&beta[c];
  f32x4 r;
#pragma unroll
  for (int j = 0; j < 4; j++) {
    const float mean = sm[j] * (1.0f / NN);
    const float var  = sq[j] * (1.0f / NN) - mean * mean;
    const float sc   = rsqrtf(var + 1e-5f) * gm[j];
    r[j] = fmaxf(v[j] * sc + (bt[j] - mean * sc), 0.0f);
  }
  *((f32x4*)out + i) = r;
}

// ---------------------------------------------------------------------------
extern "C" void kernel_launch(void* const* d_in, const int* in_sizes, int n_in,
                              void* d_out, int out_size, void* d_ws, size_t ws_size,
                              hipStream_t stream) {
  const float* x     = (const float*)d_in[0];
  const int*   ei    = (const int*)d_in[1];
  const float* ea    = (const float*)d_in[2];
  const float* W1    = (const float*)d_in[3];
  const float* b1    = (const float*)d_in[4];
  const float* W2    = (const float*)d_in[5];
  const float* b2    = (const float*)d_in[6];
  const float* gamma = (const float*)d_in[7];
  const float* beta  = (const float*)d_in[8];
  float* out = (float*)d_out;

  char* ws = (char*)d_ws;
  float*  agg    = (float*)(ws);                    // 20,480,000 B
  float*  P      = (float*)(ws + 20480000);         // 20,480,000 B
  bf16_t* Qb     = (bf16_t*)(ws + 40960000);        // 10,240,000 B
  bf16_t* xb     = (bf16_t*)(ws + 51200000);        //  5,120,000 B
  bf16_t* w1abt  = (bf16_t*)(ws + 56320000);        //    524,288 B
  bf16_t* w1ct   = (bf16_t*)(ws + 56844288);        //    262,144 B
  bf16_t* w2t    = (bf16_t*)(ws + 57106432);        //    524,288 B
  int*    deg    = (int*)(ws + 57630720);           //     40,000 B
  int*    offs   = (int*)(ws + 57670720);           //     40,000 B
  int*    cursor = (int*)(ws + 57710720);           //     40,000 B
  float*  sums   = (float*)(ws + 57750720);         //      4,096 B
  int*    eperm  = (int*)(ws + 57754816);           //  1,280,000 B
  int*    sdst   = (int*)(ws + 59034816);           //  1,280,000 B
  int*    ssrc   = (int*)(ws + 60314816);           //  1,280,000 B

  const int* srcIdx = ei;
  const int* dstIdx = ei + NE;

  k_prep<<<4096, 256, 0, stream>>>(x, W1, W2, xb, w1abt, w1ct, w2t, agg, deg, cursor, sums);
  k_deg<<<(NE + 255) / 256, 256, 0, stream>>>(dstIdx, deg);
  k_scan<<<1, 256, 0, stream>>>(deg, offs);
  k_scatter<<<(NE + 255) / 256, 256, 0, stream>>>(srcIdx, dstIdx, offs, cursor,
                                                  eperm, sdst, ssrc);
  k_pq<<<((NN + 127) / 128) * 8, 256, 0, stream>>>(xb, w1abt, b1, P, Qb);
  k_edge_gemm<<<(NE / 128) * 4, 256, 0, stream>>>(ea, w1ct, P, Qb, eperm, sdst, ssrc, agg);
  k_node_gemm<<<((NN + 127) / 128) * 4, 256, 0, stream>>>(agg, w2t, b2, deg, out, sums);
  k_bn_apply<<<(NN * OC / 4 + 255) / 256, 256, 0, stream>>>(out, sums, gamma, beta);
}